// Round 15
// baseline (7136.012 us; speedup 1.0000x reference)
//
#include <hip/hip_runtime.h>

#define NROWS 131072
#define KCB   2048
#define DIM   256

typedef unsigned int u32;
typedef unsigned long long u64;
typedef unsigned short u16;
typedef __attribute__((ext_vector_type(8))) short short8;
typedef __attribute__((ext_vector_type(16))) float f32x16;

__device__ __forceinline__ u32 fkey(float f) {
    u32 b = __float_as_uint(f);
    return (b & 0x80000000u) ? ~b : (b | 0x80000000u);
}
__device__ __forceinline__ u16 bf_rne(float x) {
    u32 u = __float_as_uint(x);
    return (u16)((u + 0x7FFFu + ((u >> 16) & 1u)) >> 16);
}
__device__ __forceinline__ void gload16(const u16* src, u16* dst) {
    __builtin_amdgcn_global_load_lds(
        (const __attribute__((address_space(1))) void*)src,
        (__attribute__((address_space(3))) void*)dst, 16, 0, 0);
}

// ---- K0: normalize rows, split bf16 hi/lo, write plane-major layout
// dst[plane][row][8]; planes 0..31 = hi k-octets, 32..63 = lo. (r7/r11-verified)
__global__ void k_prep(const float* __restrict__ src, u16* __restrict__ dst,
                       size_t planeStride) {
    __shared__ u16 L[64][264];
    const int t = threadIdx.x, w = t >> 6, lane = t & 63;
    const int rbase = blockIdx.x * 64;

    ushort4 lo_save[16];

    #pragma unroll
    for (int i = 0; i < 16; ++i) {
        int row = rbase + w * 16 + i;
        float4 v = *(const float4*)(src + (size_t)row * DIM + 4 * lane);
        float ss = v.x * v.x + v.y * v.y + v.z * v.z + v.w * v.w;
        #pragma unroll
        for (int o = 32; o > 0; o >>= 1) ss += __shfl_down(ss, o, 64);
        ss = __shfl(ss, 0, 64);
        float inv = 1.0f / fmaxf(sqrtf(ss), 1e-12f);
        float e[4] = {v.x * inv, v.y * inv, v.z * inv, v.w * inv};
        u16 hh[4], ll[4];
        #pragma unroll
        for (int q = 0; q < 4; ++q) {
            hh[q] = bf_rne(e[q]);
            float hf = __uint_as_float(((u32)hh[q]) << 16);
            ll[q] = bf_rne(e[q] - hf);
        }
        *(ushort4*)&L[w * 16 + i][4 * lane] = make_ushort4(hh[0], hh[1], hh[2], hh[3]);
        lo_save[i] = make_ushort4(ll[0], ll[1], ll[2], ll[3]);
    }
    __syncthreads();
    #pragma unroll
    for (int q = 0; q < 8; ++q) {
        int c = q * 256 + t;
        int kb = c >> 6, r = c & 63;
        short8 val = *(const short8*)&L[r][kb * 8];
        *(short8*)(dst + (size_t)kb * planeStride + (size_t)(rbase + r) * 8) = val;
    }
    __syncthreads();
    #pragma unroll
    for (int i = 0; i < 16; ++i)
        *(ushort4*)&L[w * 16 + i][4 * lane] = lo_save[i];
    __syncthreads();
    #pragma unroll
    for (int q = 0; q < 8; ++q) {
        int c = q * 256 + t;
        int kb = c >> 6, r = c & 63;
        short8 val = *(const short8*)&L[r][kb * 8];
        *(short8*)(dst + (size_t)(32 + kb) * planeStride + (size_t)(rbase + r) * 8) = val;
    }
}

// ---- K2: MFMA GEMM, 128x128 tile, 4 waves (2x2), wave-tile 64x64, BK=16.
// r12 base (659 us) + two changes:
//  (1) single barrier per chunk: stage(b^1,c+1) issued BEFORE comp(b)
//      (different buffer -> no hazard), then vmcnt(0)+barrier once.
//  (2) __launch_bounds__(256,5): 5 blocks/CU (LDS 5x32KB = 160KB exact),
//      comp restructured so peak live frags = 6 short8 -> ~100 regs total.
__launch_bounds__(256, 5)
__global__ void k_mfma(const u16* __restrict__ zpk, const u16* __restrict__ epk,
                       u64* __restrict__ rowmax, u64* __restrict__ colmax) {
    // per buffer (u16 idx): A [0,4096) = [4 planes][128 rows][8]; B [4096,8192)
    // plane order within chunk c: {hi 2c, hi 2c+1, lo 2c, lo 2c+1}
    __shared__ __align__(16) u16 lds[2][8192];
    const int t = threadIdx.x;
    const int lane = t & 63, l31 = lane & 31, lhi = lane >> 5;
    const int w = t >> 6, wr = w >> 1, wc = w & 1;

    // bijective XCD swizzle (nwg=16384, 2048/XCD)
    const int swz = (blockIdx.x & 7) * 2048 + (blockIdx.x >> 3);
    const int brow = (swz >> 4) * 128;
    const int bcol = (swz & 15) * 128;

    const size_t ZPS = (size_t)NROWS * 8;   // z plane stride (u16)
    const size_t EPS = (size_t)KCB * 8;     // e plane stride (u16)

    f32x16 acc[2][2];
    #pragma unroll
    for (int i = 0; i < 2; ++i)
        #pragma unroll
        for (int j = 0; j < 2; ++j)
            #pragma unroll
            for (int r = 0; r < 16; ++r) acc[i][j][r] = 0.f;

    auto stage = [&](int b, int c) {
        #pragma unroll
        for (int q = 0; q < 2; ++q) {
            int f = q * 256 + t;                 // 16B chunk id 0..511
            int p = f >> 7, r = f & 127;
            int gp = (p < 2) ? (2 * c + p) : (30 + 2 * c + p);   // lo: 32+2c+(p-2)
            gload16(zpk + (size_t)gp * ZPS + (size_t)(brow + r) * 8, &lds[b][f * 8]);
            gload16(epk + (size_t)gp * EPS + (size_t)(bcol + r) * 8, &lds[b][4096 + f * 8]);
        }
    };

    stage(0, 0);
    asm volatile("s_waitcnt vmcnt(0)" ::: "memory");
    __builtin_amdgcn_s_barrier();

    for (int c = 0; c < 16; ++c) {
        const int b = c & 1;
        if (c + 1 < 16) stage(b ^ 1, c + 1);   // prefetch overlaps comp below

        __builtin_amdgcn_s_setprio(1);
        // B fragments first (4 live), A fragments transient per-i (2 live)
        short8 eh[2], el[2];
        #pragma unroll
        for (int j = 0; j < 2; ++j) {
            int r = wc * 64 + j * 32 + l31;
            eh[j] = *(const short8*)&lds[b][4096 + (lhi * 128 + r) * 8];
            el[j] = *(const short8*)&lds[b][4096 + ((2 + lhi) * 128 + r) * 8];
        }
        #pragma unroll
        for (int i = 0; i < 2; ++i) {
            int r = wr * 64 + i * 32 + l31;
            short8 zh = *(const short8*)&lds[b][(lhi * 128 + r) * 8];
            short8 zl = *(const short8*)&lds[b][((2 + lhi) * 128 + r) * 8];
            #pragma unroll
            for (int j = 0; j < 2; ++j) {
                acc[i][j] = __builtin_amdgcn_mfma_f32_32x32x16_bf16(zh, eh[j], acc[i][j], 0, 0, 0);
                acc[i][j] = __builtin_amdgcn_mfma_f32_32x32x16_bf16(zl, eh[j], acc[i][j], 0, 0, 0);
                acc[i][j] = __builtin_amdgcn_mfma_f32_32x32x16_bf16(zh, el[j], acc[i][j], 0, 0, 0);
            }
        }
        __builtin_amdgcn_s_setprio(0);

        if (c + 1 < 16) { asm volatile("s_waitcnt vmcnt(0)" ::: "memory"); }
        __builtin_amdgcn_s_barrier();          // next chunk staged AND buf b free
    }

    // ---- epilogue: argmax reductions (r12-verified 2x2/64x64 semantics) ----
    float2* colred = (float2*)&lds[0][0];      // [2 wr][128 cols]
    float2* rowred = (float2*)&lds[0][1024];   // [2 wc][128 rows]

    #pragma unroll
    for (int j = 0; j < 2; ++j) {
        float bv = -3.4e38f; int brw = 0x7FFFFFFF;
        #pragma unroll
        for (int i = 0; i < 2; ++i)
            #pragma unroll
            for (int r = 0; r < 16; ++r) {
                float v = acc[i][j][r];
                int rg = brow + wr * 64 + i * 32 + (r & 3) + 8 * (r >> 2) + 4 * lhi;
                if (v > bv || (v == bv && rg < brw)) { bv = v; brw = rg; }
            }
        float ov = __shfl_xor(bv, 32); int orw = __shfl_xor(brw, 32);
        if (ov > bv || (ov == bv && orw < brw)) { bv = ov; brw = orw; }
        if (lane < 32) colred[wr * 128 + wc * 64 + j * 32 + l31] = make_float2(bv, __int_as_float(brw));
    }

    #pragma unroll
    for (int i = 0; i < 2; ++i) {
        #pragma unroll
        for (int r = 0; r < 16; ++r) {
            float bv = -3.4e38f; int bc = 0x7FFFFFFF;
            #pragma unroll
            for (int j = 0; j < 2; ++j) {
                float v = acc[i][j][r];
                int cg = bcol + wc * 64 + j * 32 + l31;
                if (v > bv || (v == bv && cg < bc)) { bv = v; bc = cg; }
            }
            #pragma unroll
            for (int m = 16; m >= 1; m >>= 1) {
                float ov = __shfl_xor(bv, m);
                int oc = __shfl_xor(bc, m);
                if (ov > bv || (ov == bv && oc < bc)) { bv = ov; bc = oc; }
            }
            if (l31 == 0) {
                int rloc = wr * 64 + i * 32 + (r & 3) + 8 * (r >> 2) + 4 * lhi;
                rowred[wc * 128 + rloc] = make_float2(bv, __int_as_float(bc));
            }
        }
    }
    __syncthreads();

    if (t < 128) {
        float2 e0 = colred[t], e1 = colred[128 + t];
        float bv = e0.x; int brw = __float_as_int(e0.y);
        if (e1.x > bv || (e1.x == bv && __float_as_int(e1.y) < brw)) { bv = e1.x; brw = __float_as_int(e1.y); }
        atomicMax(colmax + bcol + t, ((u64)fkey(bv) << 32) | (u64)(~(u32)brw));

        float2 r0 = rowred[t], r1 = rowred[128 + t];
        float rv = r0.x; int rc = __float_as_int(r0.y);
        if (r1.x > rv || (r1.x == rv && __float_as_int(r1.y) < rc)) { rv = r1.x; rc = __float_as_int(r1.y); }
        atomicMax(rowmax + brow + t, ((u64)fkey(rv) << 32) | (u64)(~(u32)rc));
    }
}

// ---- K3: gather z_q, write out0, loss partials, histogram ----
__global__ void k_gather(const float* __restrict__ z, const float* __restrict__ emb,
                         const u64* __restrict__ rowmax, float* __restrict__ zq_out,
                         int* __restrict__ counts, float* __restrict__ partials) {
    __shared__ float red[256];
    int t = threadIdx.x;
    int lane = t & 63, w = t >> 6;
    int base = blockIdx.x * 64;
    float acc = 0.f;
    for (int r = 0; r < 16; ++r) {
        int row = base + w * 16 + r;
        int ix = (int)(~(u32)(rowmax[row] & 0xFFFFFFFFull));
        float4 e  = *(const float4*)(emb + (size_t)ix * DIM + 4 * lane);
        float4 zv = *(const float4*)(z + (size_t)row * DIM + 4 * lane);
        float4 o;
        o.x = zv.x + (e.x - zv.x); o.y = zv.y + (e.y - zv.y);
        o.z = zv.z + (e.z - zv.z); o.w = zv.w + (e.w - zv.w);
        *(float4*)(zq_out + (size_t)row * DIM + 4 * lane) = o;
        float dx = e.x - zv.x, dy = e.y - zv.y, dz = e.z - zv.z, dw = e.w - zv.w;
        acc += dx * dx + dy * dy + dz * dz + dw * dw;
        if (lane == 0) atomicAdd(counts + ix, 1);
    }
    red[t] = acc;
    __syncthreads();
    #pragma unroll
    for (int o = 128; o > 0; o >>= 1) { if (t < o) red[t] += red[t + o]; __syncthreads(); }
    if (t == 0) partials[blockIdx.x] = red[0];
}

// ---- K4: final loss reduce ----
__global__ void k_loss(const float* __restrict__ partials, float* __restrict__ out_loss) {
    __shared__ float red[256];
    int t = threadIdx.x;
    float a = 0.f;
    for (int i = t; i < 2048; i += 256) a += partials[i];
    red[t] = a;
    __syncthreads();
    #pragma unroll
    for (int o = 128; o > 0; o >>= 1) { if (t < o) red[t] += red[t + o]; __syncthreads(); }
    if (t == 0) out_loss[0] = 1.25f * (red[0] / 33554432.0f);
}

// ---- K5: finalize new_embedding + new_embed_prob ----
__global__ void k_final(const float* __restrict__ z, const float* __restrict__ emb,
                        const float* __restrict__ eprob, const int* __restrict__ counts,
                        const u64* __restrict__ colmax,
                        float* __restrict__ out_emb, float* __restrict__ out_prob) {
    int k = blockIdx.x, lane = threadIdx.x;
    int r = (int)(~(u32)(colmax[k] & 0xFFFFFFFFull));
    float avg = (float)counts[k] * (1.0f / (float)NROWS);
    float nep = eprob[k] * 0.99f + avg * 0.01f;
    float reinit = expf(-(((nep * 2048.0f) * 10.0f) / 0.01f) - 0.001f);
    float4 ev = *(const float4*)(emb + (size_t)k * DIM + 4 * lane);
    float4 zv = *(const float4*)(z + (size_t)r * DIM + 4 * lane);
    float4 o;
    o.x = ev.x * (1.f - reinit) + zv.x * reinit;
    o.y = ev.y * (1.f - reinit) + zv.y * reinit;
    o.z = ev.z * (1.f - reinit) + zv.z * reinit;
    o.w = ev.w * (1.f - reinit) + zv.w * reinit;
    *(float4*)(out_emb + (size_t)k * DIM + 4 * lane) = o;
    if (lane == 0) out_prob[k] = nep;
}

extern "C" void kernel_launch(void* const* d_in, const int* in_sizes, int n_in,
                              void* d_out, int out_size, void* d_ws, size_t ws_size,
                              hipStream_t stream) {
    const float* z   = (const float*)d_in[0];
    const float* emb = (const float*)d_in[1];
    const float* epr = (const float*)d_in[2];

    float* out      = (float*)d_out;
    float* out_zq   = out;
    float* out_loss = out + (size_t)NROWS * DIM;
    float* out_emb  = out_loss + 1;
    float* out_prob = out_emb + (size_t)KCB * DIM;

    // z_pk aliases the zq region of d_out; overwritten by k_gather afterwards.
    u16* zpk = (u16*)d_out;

    char* ws = (char*)d_ws;
    u16*   epk    = (u16*)  (ws + 0);          // 2 MB
    u64*   rowmax = (u64*)  (ws + 2097152);    // 1 MB
    u64*   colmax = (u64*)  (ws + 3145728);    // 16 KB
    int*   counts = (int*)  (ws + 3162112);    // 8 KB
    float* parts  = (float*)(ws + 3170304);    // 8 KB

    hipMemsetAsync(rowmax, 0, 1048576 + 16384 + 8192, stream);

    k_prep<<<NROWS / 64, 256, 0, stream>>>(z, zpk, (size_t)NROWS * 8);
    k_prep<<<KCB / 64, 256, 0, stream>>>(emb, epk, (size_t)KCB * 8);
    k_mfma<<<(NROWS / 128) * (KCB / 128), 256, 0, stream>>>(zpk, epk, rowmax, colmax);
    k_gather<<<NROWS / 64, 256, 0, stream>>>(z, emb, rowmax, out_zq, counts, parts);
    k_loss<<<1, 256, 0, stream>>>(parts, out_loss);
    k_final<<<KCB, 64, 0, stream>>>(z, emb, epr, counts, colmax, out_emb, out_prob);
}

// Round 16
// 692.640 us; speedup vs baseline: 10.3026x; 10.3026x over previous
//
#include <hip/hip_runtime.h>

#define NROWS 131072
#define KCB   2048
#define DIM   256

typedef unsigned int u32;
typedef unsigned long long u64;
typedef unsigned short u16;
typedef __attribute__((ext_vector_type(8))) short short8;
typedef __attribute__((ext_vector_type(16))) float f32x16;

__device__ __forceinline__ u32 fkey(float f) {
    u32 b = __float_as_uint(f);
    return (b & 0x80000000u) ? ~b : (b | 0x80000000u);
}
__device__ __forceinline__ u16 bf_rne(float x) {
    u32 u = __float_as_uint(x);
    return (u16)((u + 0x7FFFu + ((u >> 16) & 1u)) >> 16);
}
__device__ __forceinline__ void gload16(const u16* src, u16* dst) {
    __builtin_amdgcn_global_load_lds(
        (const __attribute__((address_space(1))) void*)src,
        (__attribute__((address_space(3))) void*)dst, 16, 0, 0);
}

// ---- K0: normalize rows, split bf16 hi/lo, write plane-major layout
// dst[plane][row][8]; planes 0..31 = hi k-octets, 32..63 = lo. (r7/r11-verified)
__global__ void k_prep(const float* __restrict__ src, u16* __restrict__ dst,
                       size_t planeStride) {
    __shared__ u16 L[64][264];
    const int t = threadIdx.x, w = t >> 6, lane = t & 63;
    const int rbase = blockIdx.x * 64;

    ushort4 lo_save[16];

    #pragma unroll
    for (int i = 0; i < 16; ++i) {
        int row = rbase + w * 16 + i;
        float4 v = *(const float4*)(src + (size_t)row * DIM + 4 * lane);
        float ss = v.x * v.x + v.y * v.y + v.z * v.z + v.w * v.w;
        #pragma unroll
        for (int o = 32; o > 0; o >>= 1) ss += __shfl_down(ss, o, 64);
        ss = __shfl(ss, 0, 64);
        float inv = 1.0f / fmaxf(sqrtf(ss), 1e-12f);
        float e[4] = {v.x * inv, v.y * inv, v.z * inv, v.w * inv};
        u16 hh[4], ll[4];
        #pragma unroll
        for (int q = 0; q < 4; ++q) {
            hh[q] = bf_rne(e[q]);
            float hf = __uint_as_float(((u32)hh[q]) << 16);
            ll[q] = bf_rne(e[q] - hf);
        }
        *(ushort4*)&L[w * 16 + i][4 * lane] = make_ushort4(hh[0], hh[1], hh[2], hh[3]);
        lo_save[i] = make_ushort4(ll[0], ll[1], ll[2], ll[3]);
    }
    __syncthreads();
    #pragma unroll
    for (int q = 0; q < 8; ++q) {
        int c = q * 256 + t;
        int kb = c >> 6, r = c & 63;
        short8 val = *(const short8*)&L[r][kb * 8];
        *(short8*)(dst + (size_t)kb * planeStride + (size_t)(rbase + r) * 8) = val;
    }
    __syncthreads();
    #pragma unroll
    for (int i = 0; i < 16; ++i)
        *(ushort4*)&L[w * 16 + i][4 * lane] = lo_save[i];
    __syncthreads();
    #pragma unroll
    for (int q = 0; q < 8; ++q) {
        int c = q * 256 + t;
        int kb = c >> 6, r = c & 63;
        short8 val = *(const short8*)&L[r][kb * 8];
        *(short8*)(dst + (size_t)(32 + kb) * planeStride + (size_t)(rbase + r) * 8) = val;
    }
}

// ---- K2: MFMA GEMM, 128x128 tile, 4 waves (2x2), wave-tile 64x64, BK=16.
// r12 geometry (4 blocks/CU, 120 regs, no spill) + single barrier per chunk:
// stage(b^1,c+1) issued BEFORE comp(b) (different buffer -> no hazard), then
// one vmcnt(0)+s_barrier per chunk (r12 had 2 barriers + mid-wait).
__launch_bounds__(256, 4)
__global__ void k_mfma(const u16* __restrict__ zpk, const u16* __restrict__ epk,
                       u64* __restrict__ rowmax, u64* __restrict__ colmax) {
    // per buffer (u16 idx): A [0,4096) = [4 planes][128 rows][8]; B [4096,8192)
    // plane order within chunk c: {hi 2c, hi 2c+1, lo 2c, lo 2c+1}
    __shared__ __align__(16) u16 lds[2][8192];
    const int t = threadIdx.x;
    const int lane = t & 63, l31 = lane & 31, lhi = lane >> 5;
    const int w = t >> 6, wr = w >> 1, wc = w & 1;

    // bijective XCD swizzle (nwg=16384, 2048/XCD)
    const int swz = (blockIdx.x & 7) * 2048 + (blockIdx.x >> 3);
    const int brow = (swz >> 4) * 128;
    const int bcol = (swz & 15) * 128;

    const size_t ZPS = (size_t)NROWS * 8;   // z plane stride (u16)
    const size_t EPS = (size_t)KCB * 8;     // e plane stride (u16)

    f32x16 acc[2][2];
    #pragma unroll
    for (int i = 0; i < 2; ++i)
        #pragma unroll
        for (int j = 0; j < 2; ++j)
            #pragma unroll
            for (int r = 0; r < 16; ++r) acc[i][j][r] = 0.f;

    auto stage = [&](int b, int c) {
        #pragma unroll
        for (int q = 0; q < 2; ++q) {
            int f = q * 256 + t;                 // 16B chunk id 0..511
            int p = f >> 7, r = f & 127;
            int gp = (p < 2) ? (2 * c + p) : (30 + 2 * c + p);   // lo: 32+2c+(p-2)
            gload16(zpk + (size_t)gp * ZPS + (size_t)(brow + r) * 8, &lds[b][f * 8]);
            gload16(epk + (size_t)gp * EPS + (size_t)(bcol + r) * 8, &lds[b][4096 + f * 8]);
        }
    };

    stage(0, 0);
    asm volatile("s_waitcnt vmcnt(0)" ::: "memory");
    __builtin_amdgcn_s_barrier();

    for (int c = 0; c < 16; ++c) {
        const int b = c & 1;
        if (c + 1 < 16) stage(b ^ 1, c + 1);   // prefetch overlaps comp below

        // ---- comp(b): identical frag loads + MFMA order to r12 ----
        short8 zh[2], zl[2], eh[2], el[2];
        #pragma unroll
        for (int i = 0; i < 2; ++i) {
            int r = wr * 64 + i * 32 + l31;
            zh[i] = *(const short8*)&lds[b][(lhi * 128 + r) * 8];
            zl[i] = *(const short8*)&lds[b][((2 + lhi) * 128 + r) * 8];
        }
        #pragma unroll
        for (int j = 0; j < 2; ++j) {
            int r = wc * 64 + j * 32 + l31;
            eh[j] = *(const short8*)&lds[b][4096 + (lhi * 128 + r) * 8];
            el[j] = *(const short8*)&lds[b][4096 + ((2 + lhi) * 128 + r) * 8];
        }

        __builtin_amdgcn_s_setprio(1);
        #pragma unroll
        for (int i = 0; i < 2; ++i)
            #pragma unroll
            for (int j = 0; j < 2; ++j)
                acc[i][j] = __builtin_amdgcn_mfma_f32_32x32x16_bf16(zh[i], eh[j], acc[i][j], 0, 0, 0);
        #pragma unroll
        for (int i = 0; i < 2; ++i)
            #pragma unroll
            for (int j = 0; j < 2; ++j)
                acc[i][j] = __builtin_amdgcn_mfma_f32_32x32x16_bf16(zl[i], eh[j], acc[i][j], 0, 0, 0);
        #pragma unroll
        for (int i = 0; i < 2; ++i)
            #pragma unroll
            for (int j = 0; j < 2; ++j)
                acc[i][j] = __builtin_amdgcn_mfma_f32_32x32x16_bf16(zh[i], el[j], acc[i][j], 0, 0, 0);
        __builtin_amdgcn_s_setprio(0);

        if (c + 1 < 16) { asm volatile("s_waitcnt vmcnt(0)" ::: "memory"); }
        __builtin_amdgcn_s_barrier();          // next chunk staged AND buf b free
    }

    // ---- epilogue: argmax reductions (r12-verified 2x2/64x64 semantics) ----
    float2* colred = (float2*)&lds[0][0];      // [2 wr][128 cols]
    float2* rowred = (float2*)&lds[0][1024];   // [2 wc][128 rows]

    #pragma unroll
    for (int j = 0; j < 2; ++j) {
        float bv = -3.4e38f; int brw = 0x7FFFFFFF;
        #pragma unroll
        for (int i = 0; i < 2; ++i)
            #pragma unroll
            for (int r = 0; r < 16; ++r) {
                float v = acc[i][j][r];
                int rg = brow + wr * 64 + i * 32 + (r & 3) + 8 * (r >> 2) + 4 * lhi;
                if (v > bv || (v == bv && rg < brw)) { bv = v; brw = rg; }
            }
        float ov = __shfl_xor(bv, 32); int orw = __shfl_xor(brw, 32);
        if (ov > bv || (ov == bv && orw < brw)) { bv = ov; brw = orw; }
        if (lane < 32) colred[wr * 128 + wc * 64 + j * 32 + l31] = make_float2(bv, __int_as_float(brw));
    }

    #pragma unroll
    for (int i = 0; i < 2; ++i) {
        #pragma unroll
        for (int r = 0; r < 16; ++r) {
            float bv = -3.4e38f; int bc = 0x7FFFFFFF;
            #pragma unroll
            for (int j = 0; j < 2; ++j) {
                float v = acc[i][j][r];
                int cg = bcol + wc * 64 + j * 32 + l31;
                if (v > bv || (v == bv && cg < bc)) { bv = v; bc = cg; }
            }
            #pragma unroll
            for (int m = 16; m >= 1; m >>= 1) {
                float ov = __shfl_xor(bv, m);
                int oc = __shfl_xor(bc, m);
                if (ov > bv || (ov == bv && oc < bc)) { bv = ov; bc = oc; }
            }
            if (l31 == 0) {
                int rloc = wr * 64 + i * 32 + (r & 3) + 8 * (r >> 2) + 4 * lhi;
                rowred[wc * 128 + rloc] = make_float2(bv, __int_as_float(bc));
            }
        }
    }
    __syncthreads();

    if (t < 128) {
        float2 e0 = colred[t], e1 = colred[128 + t];
        float bv = e0.x; int brw = __float_as_int(e0.y);
        if (e1.x > bv || (e1.x == bv && __float_as_int(e1.y) < brw)) { bv = e1.x; brw = __float_as_int(e1.y); }
        atomicMax(colmax + bcol + t, ((u64)fkey(bv) << 32) | (u64)(~(u32)brw));

        float2 r0 = rowred[t], r1 = rowred[128 + t];
        float rv = r0.x; int rc = __float_as_int(r0.y);
        if (r1.x > rv || (r1.x == rv && __float_as_int(r1.y) < rc)) { rv = r1.x; rc = __float_as_int(r1.y); }
        atomicMax(rowmax + brow + t, ((u64)fkey(rv) << 32) | (u64)(~(u32)rc));
    }
}

// ---- K3: gather z_q, write out0, loss partials, histogram ----
__global__ void k_gather(const float* __restrict__ z, const float* __restrict__ emb,
                         const u64* __restrict__ rowmax, float* __restrict__ zq_out,
                         int* __restrict__ counts, float* __restrict__ partials) {
    __shared__ float red[256];
    int t = threadIdx.x;
    int lane = t & 63, w = t >> 6;
    int base = blockIdx.x * 64;
    float acc = 0.f;
    for (int r = 0; r < 16; ++r) {
        int row = base + w * 16 + r;
        int ix = (int)(~(u32)(rowmax[row] & 0xFFFFFFFFull));
        float4 e  = *(const float4*)(emb + (size_t)ix * DIM + 4 * lane);
        float4 zv = *(const float4*)(z + (size_t)row * DIM + 4 * lane);
        float4 o;
        o.x = zv.x + (e.x - zv.x); o.y = zv.y + (e.y - zv.y);
        o.z = zv.z + (e.z - zv.z); o.w = zv.w + (e.w - zv.w);
        *(float4*)(zq_out + (size_t)row * DIM + 4 * lane) = o;
        float dx = e.x - zv.x, dy = e.y - zv.y, dz = e.z - zv.z, dw = e.w - zv.w;
        acc += dx * dx + dy * dy + dz * dz + dw * dw;
        if (lane == 0) atomicAdd(counts + ix, 1);
    }
    red[t] = acc;
    __syncthreads();
    #pragma unroll
    for (int o = 128; o > 0; o >>= 1) { if (t < o) red[t] += red[t + o]; __syncthreads(); }
    if (t == 0) partials[blockIdx.x] = red[0];
}

// ---- K4: final loss reduce ----
__global__ void k_loss(const float* __restrict__ partials, float* __restrict__ out_loss) {
    __shared__ float red[256];
    int t = threadIdx.x;
    float a = 0.f;
    for (int i = t; i < 2048; i += 256) a += partials[i];
    red[t] = a;
    __syncthreads();
    #pragma unroll
    for (int o = 128; o > 0; o >>= 1) { if (t < o) red[t] += red[t + o]; __syncthreads(); }
    if (t == 0) out_loss[0] = 1.25f * (red[0] / 33554432.0f);
}

// ---- K5: finalize new_embedding + new_embed_prob ----
__global__ void k_final(const float* __restrict__ z, const float* __restrict__ emb,
                        const float* __restrict__ eprob, const int* __restrict__ counts,
                        const u64* __restrict__ colmax,
                        float* __restrict__ out_emb, float* __restrict__ out_prob) {
    int k = blockIdx.x, lane = threadIdx.x;
    int r = (int)(~(u32)(colmax[k] & 0xFFFFFFFFull));
    float avg = (float)counts[k] * (1.0f / (float)NROWS);
    float nep = eprob[k] * 0.99f + avg * 0.01f;
    float reinit = expf(-(((nep * 2048.0f) * 10.0f) / 0.01f) - 0.001f);
    float4 ev = *(const float4*)(emb + (size_t)k * DIM + 4 * lane);
    float4 zv = *(const float4*)(z + (size_t)r * DIM + 4 * lane);
    float4 o;
    o.x = ev.x * (1.f - reinit) + zv.x * reinit;
    o.y = ev.y * (1.f - reinit) + zv.y * reinit;
    o.z = ev.z * (1.f - reinit) + zv.z * reinit;
    o.w = ev.w * (1.f - reinit) + zv.w * reinit;
    *(float4*)(out_emb + (size_t)k * DIM + 4 * lane) = o;
    if (lane == 0) out_prob[k] = nep;
}

extern "C" void kernel_launch(void* const* d_in, const int* in_sizes, int n_in,
                              void* d_out, int out_size, void* d_ws, size_t ws_size,
                              hipStream_t stream) {
    const float* z   = (const float*)d_in[0];
    const float* emb = (const float*)d_in[1];
    const float* epr = (const float*)d_in[2];

    float* out      = (float*)d_out;
    float* out_zq   = out;
    float* out_loss = out + (size_t)NROWS * DIM;
    float* out_emb  = out_loss + 1;
    float* out_prob = out_emb + (size_t)KCB * DIM;

    // z_pk aliases the zq region of d_out; overwritten by k_gather afterwards.
    u16* zpk = (u16*)d_out;

    char* ws = (char*)d_ws;
    u16*   epk    = (u16*)  (ws + 0);          // 2 MB
    u64*   rowmax = (u64*)  (ws + 2097152);    // 1 MB
    u64*   colmax = (u64*)  (ws + 3145728);    // 16 KB
    int*   counts = (int*)  (ws + 3162112);    // 8 KB
    float* parts  = (float*)(ws + 3170304);    // 8 KB

    hipMemsetAsync(rowmax, 0, 1048576 + 16384 + 8192, stream);

    k_prep<<<NROWS / 64, 256, 0, stream>>>(z, zpk, (size_t)NROWS * 8);
    k_prep<<<KCB / 64, 256, 0, stream>>>(emb, epk, (size_t)KCB * 8);
    k_mfma<<<(NROWS / 128) * (KCB / 128), 256, 0, stream>>>(zpk, epk, rowmax, colmax);
    k_gather<<<NROWS / 64, 256, 0, stream>>>(z, emb, rowmax, out_zq, counts, parts);
    k_loss<<<1, 256, 0, stream>>>(parts, out_loss);
    k_final<<<KCB, 64, 0, stream>>>(z, emb, epr, counts, colmax, out_emb, out_prob);
}

// Round 17
// 690.196 us; speedup vs baseline: 10.3391x; 1.0035x over previous
//
#include <hip/hip_runtime.h>

#define NROWS 131072
#define KCB   2048
#define DIM   256

typedef unsigned int u32;
typedef unsigned long long u64;
typedef unsigned short u16;
typedef __attribute__((ext_vector_type(8))) short short8;
typedef __attribute__((ext_vector_type(16))) float f32x16;

__device__ __forceinline__ u32 fkey(float f) {
    u32 b = __float_as_uint(f);
    return (b & 0x80000000u) ? ~b : (b | 0x80000000u);
}
__device__ __forceinline__ u16 bf_rne(float x) {
    u32 u = __float_as_uint(x);
    return (u16)((u + 0x7FFFu + ((u >> 16) & 1u)) >> 16);
}
__device__ __forceinline__ void gload16(const u16* src, u16* dst) {
    __builtin_amdgcn_global_load_lds(
        (const __attribute__((address_space(1))) void*)src,
        (__attribute__((address_space(3))) void*)dst, 16, 0, 0);
}

// ---- K0: normalize rows, split bf16 hi/lo, write plane-major layout
// dst[plane][row][8]; planes 0..31 = hi k-octets, 32..63 = lo. (r7/r11-verified)
__global__ void k_prep(const float* __restrict__ src, u16* __restrict__ dst,
                       size_t planeStride) {
    __shared__ u16 L[64][264];
    const int t = threadIdx.x, w = t >> 6, lane = t & 63;
    const int rbase = blockIdx.x * 64;

    ushort4 lo_save[16];

    #pragma unroll
    for (int i = 0; i < 16; ++i) {
        int row = rbase + w * 16 + i;
        float4 v = *(const float4*)(src + (size_t)row * DIM + 4 * lane);
        float ss = v.x * v.x + v.y * v.y + v.z * v.z + v.w * v.w;
        #pragma unroll
        for (int o = 32; o > 0; o >>= 1) ss += __shfl_down(ss, o, 64);
        ss = __shfl(ss, 0, 64);
        float inv = 1.0f / fmaxf(sqrtf(ss), 1e-12f);
        float e[4] = {v.x * inv, v.y * inv, v.z * inv, v.w * inv};
        u16 hh[4], ll[4];
        #pragma unroll
        for (int q = 0; q < 4; ++q) {
            hh[q] = bf_rne(e[q]);
            float hf = __uint_as_float(((u32)hh[q]) << 16);
            ll[q] = bf_rne(e[q] - hf);
        }
        *(ushort4*)&L[w * 16 + i][4 * lane] = make_ushort4(hh[0], hh[1], hh[2], hh[3]);
        lo_save[i] = make_ushort4(ll[0], ll[1], ll[2], ll[3]);
    }
    __syncthreads();
    #pragma unroll
    for (int q = 0; q < 8; ++q) {
        int c = q * 256 + t;
        int kb = c >> 6, r = c & 63;
        short8 val = *(const short8*)&L[r][kb * 8];
        *(short8*)(dst + (size_t)kb * planeStride + (size_t)(rbase + r) * 8) = val;
    }
    __syncthreads();
    #pragma unroll
    for (int i = 0; i < 16; ++i)
        *(ushort4*)&L[w * 16 + i][4 * lane] = lo_save[i];
    __syncthreads();
    #pragma unroll
    for (int q = 0; q < 8; ++q) {
        int c = q * 256 + t;
        int kb = c >> 6, r = c & 63;
        short8 val = *(const short8*)&L[r][kb * 8];
        *(short8*)(dst + (size_t)(32 + kb) * planeStride + (size_t)(rbase + r) * 8) = val;
    }
}

// ---- K2: MFMA GEMM, 128x128 tile, 4 waves (2x2), wave-tile 64x64, BK=16.
// r16 schedule, VALU-stripped inner loop: 4 hoisted staging base pointers
// (compile-time chunk offsets), fully unrolled 16-chunk loop (b and every
// LDS offset constant), precomputed fragment offsets. FP order identical
// to r12/r16 (absmax check: must stay 1.907349e-6).
__launch_bounds__(256, 4)
__global__ void k_mfma(const u16* __restrict__ zpk, const u16* __restrict__ epk,
                       u64* __restrict__ rowmax, u64* __restrict__ colmax) {
    // per buffer (u16 idx): A [0,4096) = [4 planes][128 rows][8]; B [4096,8192)
    // plane order within chunk c: {hi 2c, hi 2c+1, lo 2c, lo 2c+1}
    __shared__ __align__(16) u16 lds[2][8192];
    const int t = threadIdx.x;
    const int lane = t & 63, l31 = lane & 31, lhi = lane >> 5;
    const int w = t >> 6, wr = w >> 1, wc = w & 1;

    // bijective XCD swizzle (nwg=16384, 2048/XCD)
    const int swz = (blockIdx.x & 7) * 2048 + (blockIdx.x >> 3);
    const int brow = (swz >> 4) * 128;
    const int bcol = (swz & 15) * 128;

    const size_t ZPS = (size_t)NROWS * 8;   // z plane stride (u16)
    const size_t EPS = (size_t)KCB * 8;     // e plane stride (u16)

    f32x16 acc[2][2];
    #pragma unroll
    for (int i = 0; i < 2; ++i)
        #pragma unroll
        for (int j = 0; j < 2; ++j)
            #pragma unroll
            for (int r = 0; r < 16; ++r) acc[i][j][r] = 0.f;

    // ---- hoisted staging sources (chunk 0); chunk c adds 2c*planeStride ----
    const int ph = t >> 7;          // 0..1: which of the two planes this thread loads
    const int rr = t & 127;         // row within tile
    const u16* sAh = zpk + (size_t)ph * ZPS + (size_t)(brow + rr) * 8;          // hi planes
    const u16* sAl = zpk + (size_t)(32 + ph) * ZPS + (size_t)(brow + rr) * 8;   // lo planes
    const u16* sBh = epk + (size_t)ph * EPS + (size_t)(bcol + rr) * 8;
    const u16* sBl = epk + (size_t)(32 + ph) * EPS + (size_t)(bcol + rr) * 8;
    // LDS destinations (constant per buffer)
    const int dA0 = t * 8, dA1 = (256 + t) * 8;
    const int dB0 = 4096 + t * 8, dB1 = 4096 + (256 + t) * 8;

    // ---- precomputed fragment LDS offsets (u16 idx, constant per buffer) ----
    int aH[2], aL[2], bH[2], bL[2];
    #pragma unroll
    for (int i = 0; i < 2; ++i) {
        int r = wr * 64 + i * 32 + l31;
        aH[i] = (lhi * 128 + r) * 8;
        aL[i] = ((2 + lhi) * 128 + r) * 8;
    }
    #pragma unroll
    for (int j = 0; j < 2; ++j) {
        int r = wc * 64 + j * 32 + l31;
        bH[j] = 4096 + (lhi * 128 + r) * 8;
        bL[j] = 4096 + ((2 + lhi) * 128 + r) * 8;
    }

    // stage chunk c into buffer b: 4 gloads, addresses = base + (2c)*stride
    auto stage = [&](int b, int c) {
        const size_t oz = (size_t)(2 * c) * ZPS;
        const size_t oe = (size_t)(2 * c) * EPS;
        gload16(sAh + oz, &lds[b][dA0]);
        gload16(sAl + oz, &lds[b][dA1]);
        gload16(sBh + oe, &lds[b][dB0]);
        gload16(sBl + oe, &lds[b][dB1]);
    };

    stage(0, 0);
    asm volatile("s_waitcnt vmcnt(0)" ::: "memory");
    __builtin_amdgcn_s_barrier();

    #pragma unroll
    for (int c = 0; c < 16; ++c) {
        const int b = c & 1;
        if (c + 1 < 16) stage(b ^ 1, c + 1);   // prefetch overlaps comp below

        // ---- comp(b): identical frag loads + MFMA order to r12/r16 ----
        short8 zh[2], zl[2], eh[2], el[2];
        #pragma unroll
        for (int i = 0; i < 2; ++i) {
            zh[i] = *(const short8*)&lds[b][aH[i]];
            zl[i] = *(const short8*)&lds[b][aL[i]];
        }
        #pragma unroll
        for (int j = 0; j < 2; ++j) {
            eh[j] = *(const short8*)&lds[b][bH[j]];
            el[j] = *(const short8*)&lds[b][bL[j]];
        }

        __builtin_amdgcn_s_setprio(1);
        #pragma unroll
        for (int i = 0; i < 2; ++i)
            #pragma unroll
            for (int j = 0; j < 2; ++j)
                acc[i][j] = __builtin_amdgcn_mfma_f32_32x32x16_bf16(zh[i], eh[j], acc[i][j], 0, 0, 0);
        #pragma unroll
        for (int i = 0; i < 2; ++i)
            #pragma unroll
            for (int j = 0; j < 2; ++j)
                acc[i][j] = __builtin_amdgcn_mfma_f32_32x32x16_bf16(zl[i], eh[j], acc[i][j], 0, 0, 0);
        #pragma unroll
        for (int i = 0; i < 2; ++i)
            #pragma unroll
            for (int j = 0; j < 2; ++j)
                acc[i][j] = __builtin_amdgcn_mfma_f32_32x32x16_bf16(zh[i], el[j], acc[i][j], 0, 0, 0);
        __builtin_amdgcn_s_setprio(0);

        if (c + 1 < 16) { asm volatile("s_waitcnt vmcnt(0)" ::: "memory"); }
        __builtin_amdgcn_s_barrier();          // next chunk staged AND buf b free
    }

    // ---- epilogue: argmax reductions (r12-verified 2x2/64x64 semantics) ----
    float2* colred = (float2*)&lds[0][0];      // [2 wr][128 cols]
    float2* rowred = (float2*)&lds[0][1024];   // [2 wc][128 rows]

    #pragma unroll
    for (int j = 0; j < 2; ++j) {
        float bv = -3.4e38f; int brw = 0x7FFFFFFF;
        #pragma unroll
        for (int i = 0; i < 2; ++i)
            #pragma unroll
            for (int r = 0; r < 16; ++r) {
                float v = acc[i][j][r];
                int rg = brow + wr * 64 + i * 32 + (r & 3) + 8 * (r >> 2) + 4 * lhi;
                if (v > bv || (v == bv && rg < brw)) { bv = v; brw = rg; }
            }
        float ov = __shfl_xor(bv, 32); int orw = __shfl_xor(brw, 32);
        if (ov > bv || (ov == bv && orw < brw)) { bv = ov; brw = orw; }
        if (lane < 32) colred[wr * 128 + wc * 64 + j * 32 + l31] = make_float2(bv, __int_as_float(brw));
    }

    #pragma unroll
    for (int i = 0; i < 2; ++i) {
        #pragma unroll
        for (int r = 0; r < 16; ++r) {
            float bv = -3.4e38f; int bc = 0x7FFFFFFF;
            #pragma unroll
            for (int j = 0; j < 2; ++j) {
                float v = acc[i][j][r];
                int cg = bcol + wc * 64 + j * 32 + l31;
                if (v > bv || (v == bv && cg < bc)) { bv = v; bc = cg; }
            }
            #pragma unroll
            for (int m = 16; m >= 1; m >>= 1) {
                float ov = __shfl_xor(bv, m);
                int oc = __shfl_xor(bc, m);
                if (ov > bv || (ov == bv && oc < bc)) { bv = ov; bc = oc; }
            }
            if (l31 == 0) {
                int rloc = wr * 64 + i * 32 + (r & 3) + 8 * (r >> 2) + 4 * lhi;
                rowred[wc * 128 + rloc] = make_float2(bv, __int_as_float(bc));
            }
        }
    }
    __syncthreads();

    if (t < 128) {
        float2 e0 = colred[t], e1 = colred[128 + t];
        float bv = e0.x; int brw = __float_as_int(e0.y);
        if (e1.x > bv || (e1.x == bv && __float_as_int(e1.y) < brw)) { bv = e1.x; brw = __float_as_int(e1.y); }
        atomicMax(colmax + bcol + t, ((u64)fkey(bv) << 32) | (u64)(~(u32)brw));

        float2 r0 = rowred[t], r1 = rowred[128 + t];
        float rv = r0.x; int rc = __float_as_int(r0.y);
        if (r1.x > rv || (r1.x == rv && __float_as_int(r1.y) < rc)) { rv = r1.x; rc = __float_as_int(r1.y); }
        atomicMax(rowmax + brow + t, ((u64)fkey(rv) << 32) | (u64)(~(u32)rc));
    }
}

// ---- K3: gather z_q, write out0, loss partials, histogram ----
__global__ void k_gather(const float* __restrict__ z, const float* __restrict__ emb,
                         const u64* __restrict__ rowmax, float* __restrict__ zq_out,
                         int* __restrict__ counts, float* __restrict__ partials) {
    __shared__ float red[256];
    int t = threadIdx.x;
    int lane = t & 63, w = t >> 6;
    int base = blockIdx.x * 64;
    float acc = 0.f;
    for (int r = 0; r < 16; ++r) {
        int row = base + w * 16 + r;
        int ix = (int)(~(u32)(rowmax[row] & 0xFFFFFFFFull));
        float4 e  = *(const float4*)(emb + (size_t)ix * DIM + 4 * lane);
        float4 zv = *(const float4*)(z + (size_t)row * DIM + 4 * lane);
        float4 o;
        o.x = zv.x + (e.x - zv.x); o.y = zv.y + (e.y - zv.y);
        o.z = zv.z + (e.z - zv.z); o.w = zv.w + (e.w - zv.w);
        *(float4*)(zq_out + (size_t)row * DIM + 4 * lane) = o;
        float dx = e.x - zv.x, dy = e.y - zv.y, dz = e.z - zv.z, dw = e.w - zv.w;
        acc += dx * dx + dy * dy + dz * dz + dw * dw;
        if (lane == 0) atomicAdd(counts + ix, 1);
    }
    red[t] = acc;
    __syncthreads();
    #pragma unroll
    for (int o = 128; o > 0; o >>= 1) { if (t < o) red[t] += red[t + o]; __syncthreads(); }
    if (t == 0) partials[blockIdx.x] = red[0];
}

// ---- K4: final loss reduce ----
__global__ void k_loss(const float* __restrict__ partials, float* __restrict__ out_loss) {
    __shared__ float red[256];
    int t = threadIdx.x;
    float a = 0.f;
    for (int i = t; i < 2048; i += 256) a += partials[i];
    red[t] = a;
    __syncthreads();
    #pragma unroll
    for (int o = 128; o > 0; o >>= 1) { if (t < o) red[t] += red[t + o]; __syncthreads(); }
    if (t == 0) out_loss[0] = 1.25f * (red[0] / 33554432.0f);
}

// ---- K5: finalize new_embedding + new_embed_prob ----
__global__ void k_final(const float* __restrict__ z, const float* __restrict__ emb,
                        const float* __restrict__ eprob, const int* __restrict__ counts,
                        const u64* __restrict__ colmax,
                        float* __restrict__ out_emb, float* __restrict__ out_prob) {
    int k = blockIdx.x, lane = threadIdx.x;
    int r = (int)(~(u32)(colmax[k] & 0xFFFFFFFFull));
    float avg = (float)counts[k] * (1.0f / (float)NROWS);
    float nep = eprob[k] * 0.99f + avg * 0.01f;
    float reinit = expf(-(((nep * 2048.0f) * 10.0f) / 0.01f) - 0.001f);
    float4 ev = *(const float4*)(emb + (size_t)k * DIM + 4 * lane);
    float4 zv = *(const float4*)(z + (size_t)r * DIM + 4 * lane);
    float4 o;
    o.x = ev.x * (1.f - reinit) + zv.x * reinit;
    o.y = ev.y * (1.f - reinit) + zv.y * reinit;
    o.z = ev.z * (1.f - reinit) + zv.z * reinit;
    o.w = ev.w * (1.f - reinit) + zv.w * reinit;
    *(float4*)(out_emb + (size_t)k * DIM + 4 * lane) = o;
    if (lane == 0) out_prob[k] = nep;
}

extern "C" void kernel_launch(void* const* d_in, const int* in_sizes, int n_in,
                              void* d_out, int out_size, void* d_ws, size_t ws_size,
                              hipStream_t stream) {
    const float* z   = (const float*)d_in[0];
    const float* emb = (const float*)d_in[1];
    const float* epr = (const float*)d_in[2];

    float* out      = (float*)d_out;
    float* out_zq   = out;
    float* out_loss = out + (size_t)NROWS * DIM;
    float* out_emb  = out_loss + 1;
    float* out_prob = out_emb + (size_t)KCB * DIM;

    // z_pk aliases the zq region of d_out; overwritten by k_gather afterwards.
    u16* zpk = (u16*)d_out;

    char* ws = (char*)d_ws;
    u16*   epk    = (u16*)  (ws + 0);          // 2 MB
    u64*   rowmax = (u64*)  (ws + 2097152);    // 1 MB
    u64*   colmax = (u64*)  (ws + 3145728);    // 16 KB
    int*   counts = (int*)  (ws + 3162112);    // 8 KB
    float* parts  = (float*)(ws + 3170304);    // 8 KB

    hipMemsetAsync(rowmax, 0, 1048576 + 16384 + 8192, stream);

    k_prep<<<NROWS / 64, 256, 0, stream>>>(z, zpk, (size_t)NROWS * 8);
    k_prep<<<KCB / 64, 256, 0, stream>>>(emb, epk, (size_t)KCB * 8);
    k_mfma<<<(NROWS / 128) * (KCB / 128), 256, 0, stream>>>(zpk, epk, rowmax, colmax);
    k_gather<<<NROWS / 64, 256, 0, stream>>>(z, emb, rowmax, out_zq, counts, parts);
    k_loss<<<1, 256, 0, stream>>>(parts, out_loss);
    k_final<<<KCB, 64, 0, stream>>>(z, emb, epr, counts, colmax, out_emb, out_prob);
}